// Round 1
// baseline (160.925 us; speedup 1.0000x reference)
//
#include <hip/hip_runtime.h>
#include <hip/hip_bf16.h>

// F=128, H=128, K=768, T=4, IT=2, S=57
// Factorizations used:
//  elat[i,j,:] = relu(A[i]+B[j]+b_lat), A = cf@Wel[:128], B = cf@Wel[128:]
//  new_cf[i,h] = relu(A0[i,h]+b_ne[h]+ max_{j: emask[i,j]} B0[j,h])  (relu monotone, msg>=0)

#define NK 768
#define NH 128
#define NCF 98304   // 768*128

// ---------------- K1: cf0 = relu(pf @ W_parent + b_parent), clear flag ---------
__global__ __launch_bounds__(256) void k_parent(const float* __restrict__ pf,
    const float* __restrict__ Wp, const float* __restrict__ bp,
    float* __restrict__ cf0, unsigned int* __restrict__ flag)
{
    __shared__ float s_pf[128];
    __shared__ float4 s_part[4][64];
    int t = threadIdx.x;
    if (t < 128) s_pf[t] = pf[t];
    if (blockIdx.x == 0 && t == 0) *flag = 0u;
    __syncthreads();
    int wave = t >> 6, lane = t & 63;
    int col4 = blockIdx.x * 64 + lane;          // float4-column, 0..24575
    const float4* W4 = (const float4*)Wp;       // row stride 24576 float4
    float4 acc = make_float4(0.f, 0.f, 0.f, 0.f);
    for (int f = wave * 32; f < wave * 32 + 32; ++f) {
        float4 w = W4[(size_t)f * 24576 + col4];
        float p = s_pf[f];
        acc.x = fmaf(p, w.x, acc.x);
        acc.y = fmaf(p, w.y, acc.y);
        acc.z = fmaf(p, w.z, acc.z);
        acc.w = fmaf(p, w.w, acc.w);
    }
    s_part[wave][lane] = acc;
    __syncthreads();
    if (wave == 0) {
        float4 a = s_part[0][lane], b = s_part[1][lane];
        float4 c = s_part[2][lane], d = s_part[3][lane];
        float4 bi = ((const float4*)bp)[col4];
        float4 r;
        r.x = fmaxf(a.x + b.x + c.x + d.x + bi.x, 0.f);
        r.y = fmaxf(a.y + b.y + c.y + d.y + bi.y, 0.f);
        r.z = fmaxf(a.z + b.z + c.z + d.z + bi.z, 0.f);
        r.w = fmaxf(a.w + b.w + c.w + d.w + bi.w, 0.f);
        ((float4*)cf0)[col4] = r;
    }
}

// ------------- K2: dual 768x128 @ 128x128 GEMM (+ optional exists head) --------
// Adst[k][h] = sum_r src[k][r]*W[r*128+h]
// Bdst       = sum_r src[k][r]*W[(128+r)*128+h], transposed ([h][k]) if transB
__global__ __launch_bounds__(256) void k_dualmm(const float* __restrict__ src,
    const float* __restrict__ W, float* __restrict__ Adst, float* __restrict__ Bdst,
    int transB, const float* __restrict__ Wex, const float* __restrict__ bex,
    float* __restrict__ exOut)
{
    __shared__ float s_cf[8][128];
    int t = threadIdx.x;
    int k0 = blockIdx.x * 8;
    for (int idx = t; idx < 8 * 128; idx += 256)
        s_cf[idx >> 7][idx & 127] = src[k0 * 128 + idx];
    __syncthreads();
    int h = t & 127, half = t >> 7;
    const float* Wp = W + half * 128 * 128;
    float acc[8] = {0.f,0.f,0.f,0.f,0.f,0.f,0.f,0.f};
    for (int r4 = 0; r4 < 128; r4 += 4) {
        float w0 = Wp[(r4 + 0) * 128 + h];
        float w1 = Wp[(r4 + 1) * 128 + h];
        float w2 = Wp[(r4 + 2) * 128 + h];
        float w3 = Wp[(r4 + 3) * 128 + h];
        #pragma unroll
        for (int kk = 0; kk < 8; ++kk) {
            float4 c = *(const float4*)&s_cf[kk][r4];
            acc[kk] = fmaf(c.x, w0, fmaf(c.y, w1, fmaf(c.z, w2, fmaf(c.w, w3, acc[kk]))));
        }
    }
    if (half == 0) {
        #pragma unroll
        for (int kk = 0; kk < 8; ++kk) Adst[(k0 + kk) * 128 + h] = acc[kk];
    } else if (transB) {
        #pragma unroll
        for (int kk = 0; kk < 8; ++kk) Bdst[h * NK + k0 + kk] = acc[kk];
    } else {
        #pragma unroll
        for (int kk = 0; kk < 8; ++kk) Bdst[(k0 + kk) * 128 + h] = acc[kk];
    }
    if (exOut != nullptr && t < 8) {
        float s = bex[0];
        for (int r = 0; r < 128; ++r) s = fmaf(s_cf[t][r], Wex[r], s);
        exOut[k0 + t] = s;
    }
}

// ------------- K3: edge logits + emask + any_edge -----------------------------
__global__ __launch_bounds__(256) void k_edge(const float* __restrict__ A,
    const float* __restrict__ BT, const float* __restrict__ b_lat,
    const float* __restrict__ Wex, const float* __restrict__ bex,
    const float* __restrict__ exO, float* __restrict__ edge_out,
    unsigned char* __restrict__ mask, unsigned int* __restrict__ flag)
{
    __shared__ float s_A[128][8];   // [h][i]  (A + b_lat)
    __shared__ float4 s_W4[128];    // [h] -> W_edge_ex[0..3][h]
    __shared__ float s_exi[8];
    int t = threadIdx.x;
    int i0 = blockIdx.x * 8;
    int j = blockIdx.y * 256 + t;
    for (int idx = t; idx < 1024; idx += 256) {
        int i = idx >> 7, h = idx & 127;
        s_A[h][i] = A[(i0 + i) * 128 + h] + b_lat[h];
    }
    if (t < 128) s_W4[t] = make_float4(Wex[t], Wex[128 + t], Wex[256 + t], Wex[384 + t]);
    if (t < 8) s_exi[t] = exO[i0 + t];
    __syncthreads();
    float l[8][4] = {};
    for (int h = 0; h < 128; ++h) {
        float bv = BT[h * NK + j];
        float4 w = s_W4[h];
        #pragma unroll
        for (int i = 0; i < 8; ++i) {
            float e = fmaxf(s_A[h][i] + bv, 0.f);
            l[i][0] = fmaf(e, w.x, l[i][0]);
            l[i][1] = fmaf(e, w.y, l[i][1]);
            l[i][2] = fmaf(e, w.z, l[i][2]);
            l[i][3] = fmaf(e, w.w, l[i][3]);
        }
    }
    float b0 = bex[0], b1 = bex[1], b2 = bex[2], b3 = bex[3];
    bool ej = exO[j] > 0.f;
    bool anyLocal = false;
    #pragma unroll
    for (int i = 0; i < 8; ++i) {
        float4 v = make_float4(l[i][0] + b0, l[i][1] + b1, l[i][2] + b2, l[i][3] + b3);
        ((float4*)edge_out)[(size_t)(i0 + i) * NK + j] = v;
        bool anyT = (v.x > 0.f) | (v.y > 0.f) | (v.z > 0.f) | (v.w > 0.f);
        bool m = anyT && ej && (s_exi[i] > 0.f);
        mask[(i0 + i) * NK + j] = m ? (unsigned char)1 : (unsigned char)0;
        anyLocal |= m;
    }
    unsigned long long bal = __ballot(anyLocal ? 1 : 0);
    if ((t & 63) == 0 && bal) atomicOr(flag, 1u);
}

// ------------- K5a: partial masked max over j-chunk ---------------------------
__global__ __launch_bounds__(128) void k_msgmax(const float* __restrict__ Bm,
    const unsigned char* __restrict__ mask, float* __restrict__ Mp)
{
    __shared__ float s_madd[192][8];   // 0 if masked-in else -1e30
    int t = threadIdx.x;               // = h
    int i0 = blockIdx.x * 8;
    int j0 = blockIdx.y * 192;
    for (int idx = t; idx < 1536; idx += 128) {
        int i = idx / 192, jj = idx - i * 192;
        s_madd[jj][i] = mask[(i0 + i) * NK + j0 + jj] ? 0.f : -1e30f;
    }
    __syncthreads();
    float M[8];
    #pragma unroll
    for (int i = 0; i < 8; ++i) M[i] = -1e30f;
    for (int jj = 0; jj < 192; ++jj) {
        float bv = Bm[(size_t)(j0 + jj) * 128 + t];
        const float4* mp = (const float4*)s_madd[jj];
        float4 m0 = mp[0], m1 = mp[1];
        M[0] = fmaxf(M[0], bv + m0.x);
        M[1] = fmaxf(M[1], bv + m0.y);
        M[2] = fmaxf(M[2], bv + m0.z);
        M[3] = fmaxf(M[3], bv + m0.w);
        M[4] = fmaxf(M[4], bv + m1.x);
        M[5] = fmaxf(M[5], bv + m1.y);
        M[6] = fmaxf(M[6], bv + m1.z);
        M[7] = fmaxf(M[7], bv + m1.w);
    }
    #pragma unroll
    for (int i = 0; i < 8; ++i)
        Mp[(size_t)blockIdx.y * NCF + (i0 + i) * 128 + t] = M[i];
}

// ------------- K5b: combine partials -> next cf -------------------------------
__global__ __launch_bounds__(256) void k_combine(const float* __restrict__ Mp,
    const float* __restrict__ Aadd, const float* __restrict__ bne,
    const float* __restrict__ cfp, float* __restrict__ cfn,
    const unsigned int* __restrict__ flag)
{
    int idx = blockIdx.x * 256 + threadIdx.x;
    int h = idx & 127;
    float M = fmaxf(fmaxf(Mp[idx], Mp[NCF + idx]), fmaxf(Mp[2 * NCF + idx], Mp[3 * NCF + idx]));
    float v = fmaxf(Aadd[idx] + bne[h] + M, 0.f);
    cfn[idx] = (*flag != 0u) ? v : cfp[idx];
}

// ------------- K8: final head -------------------------------------------------
__global__ __launch_bounds__(256) void k_final(const float* __restrict__ cf0,
    const float* __restrict__ cf1, const float* __restrict__ cf2,
    const float* __restrict__ Wc, const float* __restrict__ bc,
    const float* __restrict__ Wsem, const float* __restrict__ bsem,
    const float* __restrict__ W2, const float* __restrict__ b2,
    float* __restrict__ out)
{
    __shared__ float s_f[8][384];
    __shared__ float s_h[8][128];
    int t = threadIdx.x;
    int k0 = blockIdx.x * 8;
    for (int idx = t; idx < 8 * 128; idx += 256) {
        int kk = idx >> 7, h = idx & 127;
        s_f[kk][h]       = cf0[(k0 + kk) * 128 + h];
        s_f[kk][128 + h] = cf1[(k0 + kk) * 128 + h];
        s_f[kk][256 + h] = cf2[(k0 + kk) * 128 + h];
    }
    __syncthreads();
    int h = t & 127, kg = t >> 7;   // kg 0..1, rows kg*4..kg*4+3
    float acc[4] = {0.f, 0.f, 0.f, 0.f};
    for (int r4 = 0; r4 < 384; r4 += 4) {
        float w0 = Wc[(r4 + 0) * 128 + h];
        float w1 = Wc[(r4 + 1) * 128 + h];
        float w2 = Wc[(r4 + 2) * 128 + h];
        float w3 = Wc[(r4 + 3) * 128 + h];
        #pragma unroll
        for (int q = 0; q < 4; ++q) {
            float4 c = *(const float4*)&s_f[kg * 4 + q][r4];
            acc[q] = fmaf(c.x, w0, fmaf(c.y, w1, fmaf(c.z, w2, fmaf(c.w, w3, acc[q]))));
        }
    }
    float bch = bc[h];
    #pragma unroll
    for (int q = 0; q < 4; ++q) s_h[kg * 4 + q][h] = fmaxf(acc[q] + bch, 0.f);
    __syncthreads();
    // child_out = relu(h @ W2 + b2)
    float a2[4] = {0.f, 0.f, 0.f, 0.f};
    for (int r4 = 0; r4 < 128; r4 += 4) {
        float w0 = W2[(r4 + 0) * 128 + h];
        float w1 = W2[(r4 + 1) * 128 + h];
        float w2 = W2[(r4 + 2) * 128 + h];
        float w3 = W2[(r4 + 3) * 128 + h];
        #pragma unroll
        for (int q = 0; q < 4; ++q) {
            float4 c = *(const float4*)&s_h[kg * 4 + q][r4];
            a2[q] = fmaf(c.x, w0, fmaf(c.y, w1, fmaf(c.z, w2, fmaf(c.w, w3, a2[q]))));
        }
    }
    float b2h = b2[h];
    #pragma unroll
    for (int q = 0; q < 4; ++q)
        out[(size_t)(k0 + kg * 4 + q) * 128 + h] = fmaxf(a2[q] + b2h, 0.f);
    // sem logits
    for (int idx = t; idx < 8 * 57; idx += 256) {
        int kk = idx / 57, s = idx - kk * 57;
        float ss = bsem[s];
        for (int r = 0; r < 128; ++r) ss = fmaf(s_h[kk][r], Wsem[r * 57 + s], ss);
        out[98304 + (k0 + kk) * 57 + s] = ss;
    }
}

extern "C" void kernel_launch(void* const* d_in, const int* in_sizes, int n_in,
                              void* d_out, int out_size, void* d_ws, size_t ws_size,
                              hipStream_t stream) {
    const float* pf   = (const float*)d_in[0];
    const float* Wp   = (const float*)d_in[1];
    const float* bp   = (const float*)d_in[2];
    const float* Wexi = (const float*)d_in[3];
    const float* bexi = (const float*)d_in[4];
    const float* Wel  = (const float*)d_in[5];
    const float* bel  = (const float*)d_in[6];
    const float* Wee  = (const float*)d_in[7];
    const float* bee  = (const float*)d_in[8];
    const float* Wne  = (const float*)d_in[9];
    const float* bne  = (const float*)d_in[10];
    const float* Wc   = (const float*)d_in[11];
    const float* bc   = (const float*)d_in[12];
    const float* Wsem = (const float*)d_in[13];
    const float* bsem = (const float*)d_in[14];
    const float* W2   = (const float*)d_in[15];
    const float* b2   = (const float*)d_in[16];
    float* out = (float*)d_out;
    float* ws  = (float*)d_ws;
    const int N = NCF;
    float* cf0 = ws;
    float* cf1 = ws + N;
    float* cf2 = ws + 2 * N;
    float* A   = ws + 3 * N;
    float* BT  = ws + 4 * N;
    float* A0  = ws + 5 * N;
    float* B0  = ws + 6 * N;
    float* A1  = ws + 7 * N;
    float* B1  = ws + 8 * N;
    float* Mp  = ws + 9 * N;                          // 4*N floats
    unsigned char* mask = (unsigned char*)(ws + 13 * N);   // 589824 bytes
    unsigned int* flag  = (unsigned int*)(mask + 589824);

    float* out_ex   = out + 142080;
    float* out_edge = out + 142848;

    k_parent<<<384, 256, 0, stream>>>(pf, Wp, bp, cf0, flag);
    k_dualmm<<<96, 256, 0, stream>>>(cf0, Wel, A, BT, 1, Wexi, bexi, out_ex);
    k_dualmm<<<96, 256, 0, stream>>>(cf0, Wne, A0, B0, 0, nullptr, nullptr, nullptr);
    k_edge<<<dim3(96, 3), 256, 0, stream>>>(A, BT, bel, Wee, bee, out_ex, out_edge, mask, flag);
    k_msgmax<<<dim3(96, 4), 128, 0, stream>>>(B0, mask, Mp);
    k_combine<<<384, 256, 0, stream>>>(Mp, A0, bne, cf0, cf1, flag);
    k_dualmm<<<96, 256, 0, stream>>>(cf1, Wne + 32768, A1, B1, 0, nullptr, nullptr, nullptr);
    k_msgmax<<<dim3(96, 4), 128, 0, stream>>>(B1, mask, Mp);
    k_combine<<<384, 256, 0, stream>>>(Mp, A1, bne + 128, cf1, cf2, flag);
    k_final<<<96, 256, 0, stream>>>(cf0, cf1, cf2, Wc, bc, Wsem, bsem, W2, b2, out);
}

// Round 2
// 121.429 us; speedup vs baseline: 1.3253x; 1.3253x over previous
//
#include <hip/hip_runtime.h>
#include <hip/hip_bf16.h>

// F=128, H=128, K=768, T=4, IT=2, S=57
// Factorizations:
//  elat[i,j,:] = relu(A[i]+B[j]+b_lat), A = cf@Wel[:128], B = cf@Wel[128:]
//  new_cf[i,h] = relu(A0[i,h]+b_ne[h]+ max_{j: emask[i,j]} B0[j,h])

#define NK 768
#define NH 128
#define NCF 98304   // 768*128

// K1: cf0 = relu(pf @ Wp + bp); exists = cf0 @ Wexi + bexi; flag = 0
__global__ __launch_bounds__(256) void k_parent(const float* __restrict__ pf,
    const float* __restrict__ Wp, const float* __restrict__ bp,
    const float* __restrict__ Wexi, const float* __restrict__ bexi,
    float* __restrict__ cf0, float* __restrict__ exO, unsigned int* __restrict__ flag)
{
    __shared__ float s_pf[128];
    __shared__ float4 s_part[4][64];
    int t = threadIdx.x;
    if (t < 128) s_pf[t] = pf[t];
    if (blockIdx.x == 0 && t == 0) *flag = 0u;
    __syncthreads();
    int wave = t >> 6, lane = t & 63;
    int col4 = blockIdx.x * 64 + lane;          // float4-column
    const float4* W4 = (const float4*)Wp;       // row stride 24576 float4
    float4 acc = make_float4(0.f, 0.f, 0.f, 0.f);
    #pragma unroll 8
    for (int f = wave * 32; f < wave * 32 + 32; ++f) {
        float4 w = W4[(size_t)f * 24576 + col4];
        float p = s_pf[f];
        acc.x = fmaf(p, w.x, acc.x);
        acc.y = fmaf(p, w.y, acc.y);
        acc.z = fmaf(p, w.z, acc.z);
        acc.w = fmaf(p, w.w, acc.w);
    }
    s_part[wave][lane] = acc;
    __syncthreads();
    if (wave == 0) {
        float4 a = s_part[0][lane], b = s_part[1][lane];
        float4 c = s_part[2][lane], d = s_part[3][lane];
        float4 bi = ((const float4*)bp)[col4];
        float4 r;
        r.x = fmaxf(a.x + b.x + c.x + d.x + bi.x, 0.f);
        r.y = fmaxf(a.y + b.y + c.y + d.y + bi.y, 0.f);
        r.z = fmaxf(a.z + b.z + c.z + d.z + bi.z, 0.f);
        r.w = fmaxf(a.w + b.w + c.w + d.w + bi.w, 0.f);
        ((float4*)cf0)[col4] = r;
        // exists head: lanes 0..31 hold row 2b (h=4l..4l+3), 32..63 row 2b+1
        float4 w = ((const float4*)Wexi)[lane & 31];
        float dot = r.x * w.x + r.y * w.y + r.z * w.z + r.w * w.w;
        dot += __shfl_xor(dot, 16);
        dot += __shfl_xor(dot, 8);
        dot += __shfl_xor(dot, 4);
        dot += __shfl_xor(dot, 2);
        dot += __shfl_xor(dot, 1);
        if ((lane & 31) == 0) exO[2 * blockIdx.x + (lane >> 5)] = dot + bexi[0];
    }
}

// K2: dual 768x128 @ 128x128x2 GEMM. grid(192,2): y=0 -> Wel -> A, BT(transposed);
//     y=1 -> Wne0 -> A0, B0
__global__ __launch_bounds__(256) void k_dualmm(const float* __restrict__ src,
    const float* __restrict__ Wel, float* __restrict__ A, float* __restrict__ BT,
    const float* __restrict__ Wne, float* __restrict__ A0, float* __restrict__ B0)
{
    __shared__ float s_cf[4][128];
    __shared__ float s_bt[128][4];
    int t = threadIdx.x;
    int k0 = blockIdx.x * 4;
    int set = blockIdx.y;
    for (int idx = t; idx < 512; idx += 256)
        s_cf[idx >> 7][idx & 127] = src[k0 * 128 + idx];
    __syncthreads();
    int h = t & 127, half = t >> 7;
    const float* W = (set ? Wne : Wel) + half * 16384;
    float acc[4] = {0.f, 0.f, 0.f, 0.f};
    for (int r4 = 0; r4 < 128; r4 += 4) {
        float w0 = W[(r4 + 0) * 128 + h];
        float w1 = W[(r4 + 1) * 128 + h];
        float w2 = W[(r4 + 2) * 128 + h];
        float w3 = W[(r4 + 3) * 128 + h];
        #pragma unroll
        for (int q = 0; q < 4; ++q) {
            float4 c = *(const float4*)&s_cf[q][r4];
            acc[q] = fmaf(c.x, w0, fmaf(c.y, w1, fmaf(c.z, w2, fmaf(c.w, w3, acc[q]))));
        }
    }
    if (half == 0) {
        float* D = set ? A0 : A;
        #pragma unroll
        for (int q = 0; q < 4; ++q) D[(k0 + q) * 128 + h] = acc[q];
    } else if (set) {
        #pragma unroll
        for (int q = 0; q < 4; ++q) B0[(k0 + q) * 128 + h] = acc[q];
    } else {
        #pragma unroll
        for (int q = 0; q < 4; ++q) s_bt[h][q] = acc[q];
    }
    __syncthreads();
    if (set == 0 && t < 128)
        *(float4*)(BT + (size_t)t * NK + k0) = *(const float4*)&s_bt[t][0];
}

// K3: edge logits + emask + any_edge. grid(192,3), tile 4i x 256j.
__global__ __launch_bounds__(256) void k_edge(const float* __restrict__ A,
    const float* __restrict__ BT, const float* __restrict__ b_lat,
    const float* __restrict__ Wex, const float* __restrict__ bex,
    const float* __restrict__ exO, float* __restrict__ edge_out,
    unsigned char* __restrict__ mask, unsigned int* __restrict__ flag)
{
    __shared__ float s_pack[128][8];   // [h]: {a0..a3 (+b_lat), w0..w3}
    __shared__ float s_exi[4];
    int t = threadIdx.x;
    int i0 = blockIdx.x * 4;
    int j = blockIdx.y * 256 + t;
    for (int idx = t; idx < 512; idx += 256) {
        int i = idx >> 7, h = idx & 127;
        s_pack[h][i] = A[(i0 + i) * 128 + h] + b_lat[h];
    }
    if (t < 128)
        *(float4*)&s_pack[t][4] = make_float4(Wex[t], Wex[128 + t], Wex[256 + t], Wex[384 + t]);
    if (t < 4) s_exi[t] = exO[i0 + t];
    __syncthreads();
    float l[4][4] = {};
    const float* bt = BT + j;
    #pragma unroll 4
    for (int h = 0; h < 128; ++h) {
        float bv = bt[h * NK];
        float4 av = *(const float4*)&s_pack[h][0];
        float4 wv = *(const float4*)&s_pack[h][4];
        float e0 = fmaxf(av.x + bv, 0.f);
        float e1 = fmaxf(av.y + bv, 0.f);
        float e2 = fmaxf(av.z + bv, 0.f);
        float e3 = fmaxf(av.w + bv, 0.f);
        l[0][0] = fmaf(e0, wv.x, l[0][0]); l[0][1] = fmaf(e0, wv.y, l[0][1]);
        l[0][2] = fmaf(e0, wv.z, l[0][2]); l[0][3] = fmaf(e0, wv.w, l[0][3]);
        l[1][0] = fmaf(e1, wv.x, l[1][0]); l[1][1] = fmaf(e1, wv.y, l[1][1]);
        l[1][2] = fmaf(e1, wv.z, l[1][2]); l[1][3] = fmaf(e1, wv.w, l[1][3]);
        l[2][0] = fmaf(e2, wv.x, l[2][0]); l[2][1] = fmaf(e2, wv.y, l[2][1]);
        l[2][2] = fmaf(e2, wv.z, l[2][2]); l[2][3] = fmaf(e2, wv.w, l[2][3]);
        l[3][0] = fmaf(e3, wv.x, l[3][0]); l[3][1] = fmaf(e3, wv.y, l[3][1]);
        l[3][2] = fmaf(e3, wv.z, l[3][2]); l[3][3] = fmaf(e3, wv.w, l[3][3]);
    }
    float b0 = bex[0], b1 = bex[1], b2 = bex[2], b3 = bex[3];
    bool ej = exO[j] > 0.f;
    bool anyLocal = false;
    #pragma unroll
    for (int i = 0; i < 4; ++i) {
        float4 v = make_float4(l[i][0] + b0, l[i][1] + b1, l[i][2] + b2, l[i][3] + b3);
        ((float4*)edge_out)[(size_t)(i0 + i) * NK + j] = v;
        bool anyT = (v.x > 0.f) | (v.y > 0.f) | (v.z > 0.f) | (v.w > 0.f);
        bool m = anyT && ej && (s_exi[i] > 0.f);
        mask[(i0 + i) * NK + j] = m ? (unsigned char)1 : (unsigned char)0;
        anyLocal |= m;
    }
    unsigned long long bal = __ballot(anyLocal ? 1 : 0);
    if ((t & 63) == 0 && bal) atomicOr(flag, 1u);
}

// K4: partial masked max. grid(96,4), block 256 (j-range split across halves).
__global__ __launch_bounds__(256) void k_msgmax(const float* __restrict__ Bm,
    const unsigned char* __restrict__ mask, float* __restrict__ Mp)
{
    __shared__ float s_madd[192][8];   // [jj][i]: 0 if edge else -1e30
    __shared__ float s_red[8][256];
    int t = threadIdx.x;
    int h = t & 127, s = t >> 7;
    int i0 = blockIdx.x * 8;
    int j0 = blockIdx.y * 192;
    for (int idx = t; idx < 1536; idx += 256) {
        int i = idx / 192, jj = idx - i * 192;
        s_madd[jj][i] = mask[(i0 + i) * NK + j0 + jj] ? 0.f : -1e30f;
    }
    __syncthreads();
    float M[8];
    #pragma unroll
    for (int i = 0; i < 8; ++i) M[i] = -1e30f;
    const float* bp2 = Bm + (size_t)(j0 + s * 96) * 128 + h;
    #pragma unroll 2
    for (int jj = 0; jj < 96; ++jj) {
        float bv = bp2[(size_t)jj * 128];
        const float* mrow = &s_madd[s * 96 + jj][0];
        float4 m0 = *(const float4*)mrow;
        float4 m1 = *(const float4*)(mrow + 4);
        M[0] = fmaxf(M[0], bv + m0.x);
        M[1] = fmaxf(M[1], bv + m0.y);
        M[2] = fmaxf(M[2], bv + m0.z);
        M[3] = fmaxf(M[3], bv + m0.w);
        M[4] = fmaxf(M[4], bv + m1.x);
        M[5] = fmaxf(M[5], bv + m1.y);
        M[6] = fmaxf(M[6], bv + m1.z);
        M[7] = fmaxf(M[7], bv + m1.w);
    }
    #pragma unroll
    for (int i = 0; i < 8; ++i) s_red[i][t] = M[i];
    __syncthreads();
    if (s == 0) {
        #pragma unroll
        for (int i = 0; i < 8; ++i)
            Mp[(size_t)blockIdx.y * NCF + (i0 + i) * 128 + h] = fmaxf(M[i], s_red[i][128 + h]);
    }
}

// K5: combine -> cf1 (write) + GEMM Wne1 -> A1,B1. grid 192.
__global__ __launch_bounds__(256) void k_dualmm_c(const float* __restrict__ Mp,
    const float* __restrict__ A0, const float* __restrict__ bne,
    const float* __restrict__ cf0, const unsigned int* __restrict__ flag,
    float* __restrict__ cf1, const float* __restrict__ Wne1,
    float* __restrict__ A1, float* __restrict__ B1)
{
    __shared__ float s_cf[4][128];
    int t = threadIdx.x;
    int k0 = blockIdx.x * 4;
    unsigned int fl = *flag;
    for (int idx = t; idx < 512; idx += 256) {
        int kk = idx >> 7, hh = idx & 127;
        int g = (k0 + kk) * 128 + hh;
        float M = fmaxf(fmaxf(Mp[g], Mp[NCF + g]), fmaxf(Mp[2 * NCF + g], Mp[3 * NCF + g]));
        float v = fl ? fmaxf(A0[g] + bne[hh] + M, 0.f) : cf0[g];
        s_cf[kk][hh] = v;
        cf1[g] = v;
    }
    __syncthreads();
    int h = t & 127, half = t >> 7;
    const float* W = Wne1 + half * 16384;
    float acc[4] = {0.f, 0.f, 0.f, 0.f};
    for (int r4 = 0; r4 < 128; r4 += 4) {
        float w0 = W[(r4 + 0) * 128 + h];
        float w1 = W[(r4 + 1) * 128 + h];
        float w2 = W[(r4 + 2) * 128 + h];
        float w3 = W[(r4 + 3) * 128 + h];
        #pragma unroll
        for (int q = 0; q < 4; ++q) {
            float4 c = *(const float4*)&s_cf[q][r4];
            acc[q] = fmaf(c.x, w0, fmaf(c.y, w1, fmaf(c.z, w2, fmaf(c.w, w3, acc[q]))));
        }
    }
    float* D = half ? B1 : A1;
    #pragma unroll
    for (int q = 0; q < 4; ++q) D[(k0 + q) * 128 + h] = acc[q];
}

// K7: combine -> cf2 (local only) + final heads. grid 384 (2 rows/block).
__global__ __launch_bounds__(256) void k_final(const float* __restrict__ cf0,
    const float* __restrict__ cf1, const float* __restrict__ Mp,
    const float* __restrict__ A1, const float* __restrict__ bne1,
    const unsigned int* __restrict__ flag,
    const float* __restrict__ Wc, const float* __restrict__ bc,
    const float* __restrict__ Wsem, const float* __restrict__ bsem,
    const float* __restrict__ W2, const float* __restrict__ b2,
    float* __restrict__ out)
{
    __shared__ float s_f[2][384];
    __shared__ float s_h[2][128];
    int t = threadIdx.x;
    int k0 = blockIdx.x * 2;
    unsigned int fl = *flag;
    {
        int kk = t >> 7, hh = t & 127;
        int g = (k0 + kk) * 128 + hh;
        float f0 = cf0[g], f1 = cf1[g];
        float M = fmaxf(fmaxf(Mp[g], Mp[NCF + g]), fmaxf(Mp[2 * NCF + g], Mp[3 * NCF + g]));
        float v = fl ? fmaxf(A1[g] + bne1[hh] + M, 0.f) : f1;
        s_f[kk][hh] = f0;
        s_f[kk][128 + hh] = f1;
        s_f[kk][256 + hh] = v;
    }
    __syncthreads();
    int h = t & 127, kg = t >> 7;
    float acc = 0.f;
    for (int r4 = 0; r4 < 384; r4 += 4) {
        float w0 = Wc[(r4 + 0) * 128 + h];
        float w1 = Wc[(r4 + 1) * 128 + h];
        float w2 = Wc[(r4 + 2) * 128 + h];
        float w3 = Wc[(r4 + 3) * 128 + h];
        float4 c = *(const float4*)&s_f[kg][r4];
        acc = fmaf(c.x, w0, fmaf(c.y, w1, fmaf(c.z, w2, fmaf(c.w, w3, acc))));
    }
    s_h[kg][h] = fmaxf(acc + bc[h], 0.f);
    __syncthreads();
    float a2 = 0.f;
    for (int r4 = 0; r4 < 128; r4 += 4) {
        float w0 = W2[(r4 + 0) * 128 + h];
        float w1 = W2[(r4 + 1) * 128 + h];
        float w2 = W2[(r4 + 2) * 128 + h];
        float w3 = W2[(r4 + 3) * 128 + h];
        float4 c = *(const float4*)&s_h[kg][r4];
        a2 = fmaf(c.x, w0, fmaf(c.y, w1, fmaf(c.z, w2, fmaf(c.w, w3, a2))));
    }
    out[(size_t)(k0 + kg) * 128 + h] = fmaxf(a2 + b2[h], 0.f);
    if (t < 114) {
        int kk = t / 57, sidx = t - kk * 57;
        float ss = bsem[sidx];
        for (int r = 0; r < 128; ++r)
            ss = fmaf(s_h[kk][r], Wsem[r * 57 + sidx], ss);
        out[98304 + (k0 + kk) * 57 + sidx] = ss;
    }
}

extern "C" void kernel_launch(void* const* d_in, const int* in_sizes, int n_in,
                              void* d_out, int out_size, void* d_ws, size_t ws_size,
                              hipStream_t stream) {
    const float* pf   = (const float*)d_in[0];
    const float* Wp   = (const float*)d_in[1];
    const float* bp   = (const float*)d_in[2];
    const float* Wexi = (const float*)d_in[3];
    const float* bexi = (const float*)d_in[4];
    const float* Wel  = (const float*)d_in[5];
    const float* bel  = (const float*)d_in[6];
    const float* Wee  = (const float*)d_in[7];
    const float* bee  = (const float*)d_in[8];
    const float* Wne  = (const float*)d_in[9];
    const float* bne  = (const float*)d_in[10];
    const float* Wc   = (const float*)d_in[11];
    const float* bc   = (const float*)d_in[12];
    const float* Wsem = (const float*)d_in[13];
    const float* bsem = (const float*)d_in[14];
    const float* W2   = (const float*)d_in[15];
    const float* b2   = (const float*)d_in[16];
    float* out = (float*)d_out;
    float* ws  = (float*)d_ws;
    const int N = NCF;
    float* cf0 = ws;
    float* cf1 = ws + N;
    float* A   = ws + 2 * N;
    float* BT  = ws + 3 * N;
    float* A0  = ws + 4 * N;
    float* B0  = ws + 5 * N;
    float* A1  = ws + 6 * N;
    float* B1  = ws + 7 * N;
    float* Mp  = ws + 8 * N;                               // 4*N floats
    unsigned char* mask = (unsigned char*)(ws + 12 * N);   // 589824 bytes
    unsigned int* flag  = (unsigned int*)(mask + 589824);

    float* out_ex   = out + 142080;
    float* out_edge = out + 142848;

    k_parent<<<384, 256, 0, stream>>>(pf, Wp, bp, Wexi, bexi, cf0, out_ex, flag);
    k_dualmm<<<dim3(192, 2), 256, 0, stream>>>(cf0, Wel, A, BT, Wne, A0, B0);
    k_edge<<<dim3(192, 3), 256, 0, stream>>>(A, BT, bel, Wee, bee, out_ex, out_edge, mask, flag);
    k_msgmax<<<dim3(96, 4), 256, 0, stream>>>(B0, mask, Mp);
    k_dualmm_c<<<192, 256, 0, stream>>>(Mp, A0, bne, cf0, flag, cf1, Wne + 32768, A1, B1);
    k_msgmax<<<dim3(96, 4), 256, 0, stream>>>(B1, mask, Mp);
    k_final<<<384, 256, 0, stream>>>(cf0, cf1, Mp, A1, bne + 128, flag,
                                     Wc, bc, Wsem, bsem, W2, b2, out);
}